// Round 1
// 235.647 us; speedup vs baseline: 1.0719x; 1.0719x over previous
//
#include <hip/hip_runtime.h>
#include <hip/hip_bf16.h>

#define NN 100000
#define NE 1600000
#define NBUK 782      // ceil(NN/128): dst buckets of 128 nodes
#define NBLK 400      // edge partition blocks
#define CHUNK 4000    // edges per partition block (400*4000 = NE)
#define NGB 1563      // ceil(NN/64): blocks for MFMA GEMMs

typedef unsigned short ushort_t;
typedef __bf16 bf16x8 __attribute__((ext_vector_type(8)));
typedef float  f32x4  __attribute__((ext_vector_type(4)));

static __device__ __forceinline__ float bf2f(unsigned u) {     // low 16 bits -> f32
    union { unsigned i; float f; } c; c.i = u << 16; return c.f;
}
static __device__ __forceinline__ float bf2f_hi(unsigned u) {  // high 16 bits in place
    union { unsigned i; float f; } c; c.i = u & 0xffff0000u; return c.f;
}
static __device__ __forceinline__ ushort_t f2bf(float f) {
    union { __hip_bfloat16 b; ushort_t u; } c; c.b = __float2bfloat16(f); return c.u;
}

// ---- per-block bucket histogram (LDS int atomics only) ----
__global__ __launch_bounds__(256) void k_part_hist(const int* __restrict__ dst,
                                                   int* __restrict__ bhist) {
    __shared__ int h[NBUK];
    int t = threadIdx.x, b = blockIdx.x;
    for (int i = t; i < NBUK; i += 256) h[i] = 0;
    __syncthreads();
    int e0 = b * CHUNK;
    for (int r = 0; r < CHUNK; r += 256)
        if (r + t < CHUNK) atomicAdd(&h[dst[e0 + r + t] >> 7], 1);
    __syncthreads();
    for (int i = t; i < NBUK; i += 256) bhist[b * NBUK + i] = h[i];
}

// ---- per-bucket scan across blocks ----
__global__ __launch_bounds__(512) void k_colscan(const int* __restrict__ bhist,
                                                 int* __restrict__ base_excl,
                                                 int* __restrict__ coltot) {
    __shared__ int s[512];
    int k = blockIdx.x, t = threadIdx.x;
    int v = (t < NBLK) ? bhist[t * NBUK + k] : 0;
    s[t] = v;
    __syncthreads();
#pragma unroll
    for (int o = 1; o < 512; o <<= 1) {
        int x = (t >= o) ? s[t - o] : 0;
        __syncthreads();
        s[t] += x;
        __syncthreads();
    }
    if (t < NBLK) base_excl[t * NBUK + k] = s[t] - v;
    if (t == 511) coltot[k] = s[511];
}

// ---- exclusive scan of bucket totals ----
__global__ __launch_bounds__(1024) void k_scanb2(const int* __restrict__ coltot,
                                                 int* __restrict__ bstart,
                                                 int* __restrict__ bcnt) {
    __shared__ int s[1024];
    int t = threadIdx.x;
    int v = (t < NBUK) ? coltot[t] : 0;
    s[t] = v;
    __syncthreads();
#pragma unroll
    for (int o = 1; o < 1024; o <<= 1) {
        int x = (t >= o) ? s[t - o] : 0;
        __syncthreads();
        s[t] += x;
        __syncthreads();
    }
    if (t < NBUK) { bstart[t] = s[t] - v; bcnt[t] = v; }
}

// ---- deterministic partition: ebuf[pos] = src | (dst&127)<<17 ----
__global__ __launch_bounds__(256) void k_scatter2(const int* __restrict__ ei,
                                                  const int* __restrict__ bstart,
                                                  const int* __restrict__ base_excl,
                                                  unsigned* __restrict__ ebuf) {
    __shared__ int cur[NBUK];
    int t = threadIdx.x, b = blockIdx.x;
    for (int i = t; i < NBUK; i += 256) cur[i] = 0;
    __syncthreads();
    int e0 = b * CHUNK;
    for (int r = 0; r < CHUNK; r += 256) {
        if (r + t < CHUNK) {
            int e = e0 + r + t;
            int sv = ei[e];
            int dv = ei[NE + e];
            int k = dv >> 7;
            int rk = atomicAdd(&cur[k], 1);   // LDS int atomic
            int pos = bstart[k] + base_excl[b * NBUK + k] + rk;
            ebuf[pos] = (unsigned)sv | ((unsigned)(dv & 127) << 17);
        }
    }
}

// ---- per-bucket counting sort -> dst-sorted csr, offsets/deg/dinv ----
__global__ __launch_bounds__(256) void k_sort(const int* __restrict__ bstart,
                                              const int* __restrict__ bcnt,
                                              const unsigned* __restrict__ ebuf,
                                              int* __restrict__ csr,
                                              int* __restrict__ offsets,
                                              int* __restrict__ deg,
                                              float* __restrict__ dinv) {
    __shared__ int hist[128];
    __shared__ int off[128];
    __shared__ int cur[128];
    int t = threadIdx.x, b = blockIdx.x;
    if (t < 128) hist[t] = 0;
    __syncthreads();
    int base = bstart[b], ne = bcnt[b];
    for (int i = t; i < ne; i += 256) atomicAdd(&hist[ebuf[base + i] >> 17], 1);
    __syncthreads();
    if (t < 128) off[t] = hist[t];
    __syncthreads();
#pragma unroll
    for (int o = 1; o < 128; o <<= 1) {
        int x = 0;
        if (t < 128 && t >= o) x = off[t - o];
        __syncthreads();
        if (t < 128) off[t] += x;
        __syncthreads();
    }
    if (t < 128) {
        int excl = off[t] - hist[t];
        cur[t] = excl;
        int node = b * 128 + t;
        if (node < NN) {
            offsets[node] = base + excl;   // absolute csr index
            deg[node]     = hist[t];
            dinv[node]    = rsqrtf((float)(hist[t] + 1));
        }
    }
    __syncthreads();
    for (int i = t; i < ne; i += 256) {
        unsigned pe = ebuf[base + i];
        int dl = pe >> 17;
        int pos = atomicAdd(&cur[dl], 1);  // LDS int atomic
        csr[base + pos] = (int)(pe & 0x1FFFF);
    }
}

// ---- one-shot weight prep: W^T and W2^T as bf16 (lives in dead ebuf region) ----
__global__ __launch_bounds__(256) void k_wprep(const float* __restrict__ Wc,
                                               const float* __restrict__ Wl,
                                               ushort_t* __restrict__ wtb,
                                               ushort_t* __restrict__ w2tb) {
    int t = blockIdx.x * 256 + threadIdx.x;        // 0..8191
    int d = t & 63, k = t >> 6;                    // Wc[k][d], k<128
    wtb[d * 128 + k] = f2bf(Wc[t]);
    int j = t & 127, k2 = t >> 7;                  // Wl[k2][j], k2<64
    w2tb[j * 64 + k2] = f2bf(Wl[t]);
}

// ---- MFMA GEMM 1 (LDS-free): hp[n][d] = bf16( dinv[n] * sum_k x[n][k] W[k][d] )
// A = W^T (d x k, bf16, L1/L2-hot), B = x rows (node per l15); D: row=d-local, col=node
__global__ __launch_bounds__(256) void k_gemm1(const float* __restrict__ x,
                                               const ushort_t* __restrict__ wtb,
                                               const float* __restrict__ dinv,
                                               ushort_t* __restrict__ hp) {
    int t = threadIdx.x;
    int w = t >> 6, lane = t & 63, l15 = lane & 15, quad = lane >> 4;
    int gn = blockIdx.x * 64 + w * 16 + l15;
    int gnc = gn < NN ? gn : NN - 1;
    const float*    xp = x   + (size_t)gnc * 128 + quad * 8;
    const ushort_t* wp = wtb + l15 * 128 + quad * 8;
    f32x4 acc[4];
#pragma unroll
    for (int dt = 0; dt < 4; ++dt) { acc[dt][0]=0.f; acc[dt][1]=0.f; acc[dt][2]=0.f; acc[dt][3]=0.f; }

#pragma unroll
    for (int kt = 0; kt < 4; ++kt) {
        float4 v0 = *(const float4*)(xp + kt * 32);
        float4 v1 = *(const float4*)(xp + kt * 32 + 4);
        union { ushort_t u[8]; bf16x8 v; } cv;
        cv.u[0]=f2bf(v0.x); cv.u[1]=f2bf(v0.y); cv.u[2]=f2bf(v0.z); cv.u[3]=f2bf(v0.w);
        cv.u[4]=f2bf(v1.x); cv.u[5]=f2bf(v1.y); cv.u[6]=f2bf(v1.z); cv.u[7]=f2bf(v1.w);
        bf16x8 bv = cv.v;
#pragma unroll
        for (int dt = 0; dt < 4; ++dt) {
            bf16x8 av = *(const bf16x8*)(wp + dt * 16 * 128 + kt * 32);
            acc[dt] = __builtin_amdgcn_mfma_f32_16x16x32_bf16(av, bv, acc[dt], 0, 0, 0);
        }
    }
    if (gn < NN) {
        float dv = dinv[gn];
#pragma unroll
        for (int dt = 0; dt < 4; ++dt) {
            // D row = quad*4+reg (d-local), col = l15 (node) -> 4 consecutive d per lane
            uint2 o;
            o.x = (unsigned)f2bf(dv * acc[dt][0]) | ((unsigned)f2bf(dv * acc[dt][1]) << 16);
            o.y = (unsigned)f2bf(dv * acc[dt][2]) | ((unsigned)f2bf(dv * acc[dt][3]) << 16);
            *(uint2*)&hp[(size_t)gn * 64 + dt * 16 + quad * 4] = o;
        }
    }
}

// ---- gather-side aggregation: one wave per node; 4 lane-groups x uint2 -> 4 edges/load
__global__ __launch_bounds__(256) void k_gather(const int* __restrict__ offsets,
                                                const int* __restrict__ deg,
                                                const int* __restrict__ csr,
                                                const float* __restrict__ dinv,
                                                const ushort_t* __restrict__ hp,
                                                const float* __restrict__ b_conv,
                                                ushort_t* __restrict__ a) {
    int node = __builtin_amdgcn_readfirstlane((blockIdx.x * 256 + threadIdx.x) >> 6);
    int lane = threadIdx.x & 63;
    int g   = lane >> 4;          // edge-slot group 0..3
    int l16 = lane & 15;          // column group: cols 4*l16 .. 4*l16+3
    int start = offsets[node];
    int cnt   = deg[node];
    const ushort_t* hpc = hp + l16 * 4;

    float s0 = 0.f, s1 = 0.f, s2 = 0.f, s3 = 0.f;
#pragma unroll 1
    for (int j0 = 0; j0 < cnt; j0 += 64) {
        int m = cnt - j0; m = m < 64 ? m : 64;   // wave-uniform
        int col = 0;
        if (lane < m) col = csr[start + j0 + lane];
#pragma unroll 2
        for (int jj = 0; jj < m; jj += 16) {
            int e0 = jj + g, e1 = jj + 4 + g, e2 = jj + 8 + g, e3 = jj + 12 + g;
            int c0 = __shfl(col, e0, 64);
            int c1 = __shfl(col, e1, 64);
            int c2 = __shfl(col, e2, 64);
            int c3 = __shfl(col, e3, 64);
            uint2 d0 = *(const uint2*)(hpc + (size_t)c0 * 64);
            uint2 d1 = *(const uint2*)(hpc + (size_t)c1 * 64);
            uint2 d2 = *(const uint2*)(hpc + (size_t)c2 * 64);
            uint2 d3 = *(const uint2*)(hpc + (size_t)c3 * 64);
            if (e0 >= m) { d0.x = 0u; d0.y = 0u; }
            if (e1 >= m) { d1.x = 0u; d1.y = 0u; }
            if (e2 >= m) { d2.x = 0u; d2.y = 0u; }
            if (e3 >= m) { d3.x = 0u; d3.y = 0u; }
            s0 += bf2f(d0.x);    s1 += bf2f_hi(d0.x);
            s2 += bf2f(d0.y);    s3 += bf2f_hi(d0.y);
            s0 += bf2f(d1.x);    s1 += bf2f_hi(d1.x);
            s2 += bf2f(d1.y);    s3 += bf2f_hi(d1.y);
            s0 += bf2f(d2.x);    s1 += bf2f_hi(d2.x);
            s2 += bf2f(d2.y);    s3 += bf2f_hi(d2.y);
            s0 += bf2f(d3.x);    s1 += bf2f_hi(d3.x);
            s2 += bf2f(d3.y);    s3 += bf2f_hi(d3.y);
        }
    }
    // reduce the 4 edge-groups (lanes l16, l16+16, l16+32, l16+48)
    s0 += __shfl_xor(s0, 16, 64); s1 += __shfl_xor(s1, 16, 64);
    s2 += __shfl_xor(s2, 16, 64); s3 += __shfl_xor(s3, 16, 64);
    s0 += __shfl_xor(s0, 32, 64); s1 += __shfl_xor(s1, 32, 64);
    s2 += __shfl_xor(s2, 32, 64); s3 += __shfl_xor(s3, 32, 64);

    // self-loop + bias + relu
    uint2 sl = *(const uint2*)(hpc + (size_t)node * 64);
    s0 += bf2f(sl.x); s1 += bf2f_hi(sl.x); s2 += bf2f(sl.y); s3 += bf2f_hi(sl.y);
    float dv = dinv[node];
    float4 bc = *(const float4*)(b_conv + l16 * 4);
    float v0 = fmaxf(dv * s0 + bc.x, 0.f);
    float v1 = fmaxf(dv * s1 + bc.y, 0.f);
    float v2 = fmaxf(dv * s2 + bc.z, 0.f);
    float v3 = fmaxf(dv * s3 + bc.w, 0.f);
    if (lane < 16) {
        uint2 o;
        o.x = (unsigned)f2bf(v0) | ((unsigned)f2bf(v1) << 16);
        o.y = (unsigned)f2bf(v2) | ((unsigned)f2bf(v3) << 16);
        *(uint2*)&a[(size_t)node * 64 + l16 * 4] = o;
    }
}

// ---- MFMA epilogue GEMM (LDS-free): out[n][j] = sum_k a[n][k] W2[k][j] + b_lin[j]
// A = W2^T (j x k, bf16), B = a rows (node per l15); lane owns 4 consecutive j -> float4 store
__global__ __launch_bounds__(256) void k_epi(const ushort_t* __restrict__ a,
                                             const ushort_t* __restrict__ w2tb,
                                             const float* __restrict__ blin,
                                             float* __restrict__ out) {
    int t = threadIdx.x;
    int w = t >> 6, lane = t & 63, l15 = lane & 15, quad = lane >> 4;
    int gn = blockIdx.x * 64 + w * 16 + l15;
    int gnc = gn < NN ? gn : NN - 1;
    const ushort_t* ap = a    + (size_t)gnc * 64 + quad * 8;
    const ushort_t* wp = w2tb + l15 * 64 + quad * 8;
    f32x4 acc[8];
#pragma unroll
    for (int jt = 0; jt < 8; ++jt) { acc[jt][0]=0.f; acc[jt][1]=0.f; acc[jt][2]=0.f; acc[jt][3]=0.f; }

#pragma unroll
    for (int kt = 0; kt < 2; ++kt) {
        bf16x8 bv = *(const bf16x8*)(ap + kt * 32);
#pragma unroll
        for (int jt = 0; jt < 8; ++jt) {
            bf16x8 av = *(const bf16x8*)(wp + jt * 16 * 64 + kt * 32);
            acc[jt] = __builtin_amdgcn_mfma_f32_16x16x32_bf16(av, bv, acc[jt], 0, 0, 0);
        }
    }
    if (gn < NN) {
#pragma unroll
        for (int jt = 0; jt < 8; ++jt) {
            int j0 = jt * 16 + quad * 4;
            float4 b4 = *(const float4*)(blin + j0);
            float4 o;
            o.x = acc[jt][0] + b4.x; o.y = acc[jt][1] + b4.y;
            o.z = acc[jt][2] + b4.z; o.w = acc[jt][3] + b4.w;
            *(float4*)&out[(size_t)gn * 128 + j0] = o;
        }
    }
}

extern "C" void kernel_launch(void* const* d_in, const int* in_sizes, int n_in,
                              void* d_out, int out_size, void* d_ws, size_t ws_size,
                              hipStream_t stream) {
    const float* x  = (const float*)d_in[0];
    const int*   ei = (const int*)d_in[1];
    const float* Wc = (const float*)d_in[2];
    const float* bc = (const float*)d_in[3];
    const float* Wl = (const float*)d_in[4];
    const float* bl = (const float*)d_in[5];
    float* out = (float*)d_out;

    char* ws = (char*)d_ws;
    // total 42.1 MB; every byte written before read -> no memset needed
    int*      bhist     = (int*)(ws + 0);              // 1251200
    int*      base_excl = (int*)(ws + 1251200);        // 1251200
    int*      coltot    = (int*)(ws + 2502400);        // 3200
    int*      bstart    = (int*)(ws + 2505600);        // 3200
    int*      bcnt      = (int*)(ws + 2508800);        // 3200
    int*      offsets   = (int*)(ws + 2512000);        // 400384
    int*      deg       = (int*)(ws + 2912384);        // 400384
    float*    dinv      = (float*)(ws + 3312768);      // 400384
    unsigned* ebuf      = (unsigned*)(ws + 3713152);   // 6400000
    int*      csr       = (int*)(ws + 10113152);       // 6400000
    ushort_t* hp        = (ushort_t*)(ws + 16513152);  // 12800000 (bf16)
    ushort_t* a         = (ushort_t*)(ws + 29313152);  // 12800000 (bf16)
    // wtb/w2tb reuse the ebuf region, which is dead after k_sort (32 KB total)
    ushort_t* wtb  = (ushort_t*)(ws + 3713152);        // 16384
    ushort_t* w2tb = wtb + 8192;                       // 16384

    k_part_hist<<<NBLK, 256, 0, stream>>>(ei + NE, bhist);
    k_colscan <<<NBUK, 512, 0, stream>>>(bhist, base_excl, coltot);
    k_scanb2  <<<1, 1024, 0, stream>>>(coltot, bstart, bcnt);
    k_scatter2<<<NBLK, 256, 0, stream>>>(ei, bstart, base_excl, ebuf);
    k_sort    <<<NBUK, 256, 0, stream>>>(bstart, bcnt, ebuf, csr, offsets, deg, dinv);
    k_wprep   <<<32, 256, 0, stream>>>(Wc, Wl, wtb, w2tb);   // after k_sort: overwrites ebuf
    k_gemm1   <<<NGB, 256, 0, stream>>>(x, wtb, dinv, hp);
    k_gather  <<<NN * 64 / 256, 256, 0, stream>>>(offsets, deg, csr, dinv, hp, bc, a);
    k_epi     <<<NGB, 256, 0, stream>>>(a, w2tb, bl, out);
}

// Round 2
// 235.056 us; speedup vs baseline: 1.0746x; 1.0025x over previous
//
#include <hip/hip_runtime.h>
#include <hip/hip_bf16.h>

#define NN 100000
#define NE 1600000
#define NBUK 782      // ceil(NN/128): dst buckets of 128 nodes
#define NBLK 1600     // edge partition blocks
#define CHUNK 1000    // edges per partition block (1600*1000 = NE)
#define NGB 1563      // ceil(NN/64): blocks for MFMA GEMMs

typedef unsigned short ushort_t;
typedef __bf16 bf16x8 __attribute__((ext_vector_type(8)));
typedef float  f32x4  __attribute__((ext_vector_type(4)));

static __device__ __forceinline__ float bf2f(unsigned u) {     // low 16 bits -> f32
    union { unsigned i; float f; } c; c.i = u << 16; return c.f;
}
static __device__ __forceinline__ float bf2f_hi(unsigned u) {  // high 16 bits in place
    union { unsigned i; float f; } c; c.i = u & 0xffff0000u; return c.f;
}
static __device__ __forceinline__ ushort_t f2bf(float f) {
    union { __hip_bfloat16 b; ushort_t u; } c; c.b = __float2bfloat16(f); return c.u;
}

// ---- launch 1: per-block bucket histogram (blocks 0..NBLK-1) + weight prep (last 32 blocks)
__global__ __launch_bounds__(256) void k_pre(const int* __restrict__ ei,
                                             const float* __restrict__ Wc,
                                             const float* __restrict__ Wl,
                                             int* __restrict__ bhist,
                                             ushort_t* __restrict__ wtb,
                                             ushort_t* __restrict__ w2tb) {
    int b = blockIdx.x, t = threadIdx.x;
    if (b >= NBLK) {                       // weight prep: 32 blocks x 256 = 8192 threads
        int i = (b - NBLK) * 256 + t;
        int d = i & 63, k = i >> 6;        // Wc[k][d], k<128
        wtb[d * 128 + k] = f2bf(Wc[i]);
        int j = i & 127, k2 = i >> 7;      // Wl[k2][j], k2<64
        w2tb[j * 64 + k2] = f2bf(Wl[i]);
        return;
    }
    __shared__ int h[NBUK];
    for (int i = t; i < NBUK; i += 256) h[i] = 0;
    __syncthreads();
    const int* dst = ei + NE;
    int e0 = b * CHUNK;
    for (int r = t; r < CHUNK; r += 256) atomicAdd(&h[dst[e0 + r] >> 7], 1);
    __syncthreads();
    for (int i = t; i < NBUK; i += 256) bhist[b * NBUK + i] = h[i];
}

// ---- per-bucket scan across 1600 blocks (4 rows per thread) ----
__global__ __launch_bounds__(512) void k_colscan(const int* __restrict__ bhist,
                                                 int* __restrict__ base_excl,
                                                 int* __restrict__ coltot) {
    __shared__ int s[512];
    int k = blockIdx.x, t = threadIdx.x;
    int v0 = 0, v1 = 0, v2 = 0, v3 = 0;
    if (t < 400) {
        v0 = bhist[(4 * t + 0) * NBUK + k];
        v1 = bhist[(4 * t + 1) * NBUK + k];
        v2 = bhist[(4 * t + 2) * NBUK + k];
        v3 = bhist[(4 * t + 3) * NBUK + k];
    }
    int tsum = v0 + v1 + v2 + v3;
    s[t] = tsum;
    __syncthreads();
#pragma unroll
    for (int o = 1; o < 512; o <<= 1) {
        int x = (t >= o) ? s[t - o] : 0;
        __syncthreads();
        s[t] += x;
        __syncthreads();
    }
    if (t < 400) {
        int excl = s[t] - tsum;
        base_excl[(4 * t + 0) * NBUK + k] = excl;
        base_excl[(4 * t + 1) * NBUK + k] = excl + v0;
        base_excl[(4 * t + 2) * NBUK + k] = excl + v0 + v1;
        base_excl[(4 * t + 3) * NBUK + k] = excl + v0 + v1 + v2;
    }
    if (t == 511) coltot[k] = s[511];
}

// ---- exclusive scan of bucket totals ----
__global__ __launch_bounds__(1024) void k_scanb2(const int* __restrict__ coltot,
                                                 int* __restrict__ bstart,
                                                 int* __restrict__ bcnt) {
    __shared__ int s[1024];
    int t = threadIdx.x;
    int v = (t < NBUK) ? coltot[t] : 0;
    s[t] = v;
    __syncthreads();
#pragma unroll
    for (int o = 1; o < 1024; o <<= 1) {
        int x = (t >= o) ? s[t - o] : 0;
        __syncthreads();
        s[t] += x;
        __syncthreads();
    }
    if (t < NBUK) { bstart[t] = s[t] - v; bcnt[t] = v; }
}

// ---- deterministic partition: ebuf[pos] = src | (dst&127)<<17 ----
__global__ __launch_bounds__(256) void k_scatter2(const int* __restrict__ ei,
                                                  const int* __restrict__ bstart,
                                                  const int* __restrict__ base_excl,
                                                  unsigned* __restrict__ ebuf) {
    __shared__ int cur[NBUK];
    int t = threadIdx.x, b = blockIdx.x;
    for (int i = t; i < NBUK; i += 256) cur[i] = 0;
    __syncthreads();
    int e0 = b * CHUNK;
    for (int r = t; r < CHUNK; r += 256) {
        int e = e0 + r;
        int sv = ei[e];
        int dv = ei[NE + e];
        int k = dv >> 7;
        int rk = atomicAdd(&cur[k], 1);   // LDS int atomic
        int pos = bstart[k] + base_excl[b * NBUK + k] + rk;
        ebuf[pos] = (unsigned)sv | ((unsigned)(dv & 127) << 17);
    }
}

// ---- per-bucket counting sort -> dst-sorted csr, offsets/deg/dinv ----
__global__ __launch_bounds__(256) void k_sort(const int* __restrict__ bstart,
                                              const int* __restrict__ bcnt,
                                              const unsigned* __restrict__ ebuf,
                                              int* __restrict__ csr,
                                              int* __restrict__ offsets,
                                              int* __restrict__ deg,
                                              float* __restrict__ dinv) {
    __shared__ int hist[128];
    __shared__ int off[128];
    __shared__ int cur[128];
    int t = threadIdx.x, b = blockIdx.x;
    if (t < 128) hist[t] = 0;
    __syncthreads();
    int base = bstart[b], ne = bcnt[b];
    for (int i = t; i < ne; i += 256) atomicAdd(&hist[ebuf[base + i] >> 17], 1);
    __syncthreads();
    if (t < 128) off[t] = hist[t];
    __syncthreads();
#pragma unroll
    for (int o = 1; o < 128; o <<= 1) {
        int x = 0;
        if (t < 128 && t >= o) x = off[t - o];
        __syncthreads();
        if (t < 128) off[t] += x;
        __syncthreads();
    }
    if (t < 128) {
        int excl = off[t] - hist[t];
        cur[t] = excl;
        int node = b * 128 + t;
        if (node < NN) {
            offsets[node] = base + excl;   // absolute csr index
            deg[node]     = hist[t];
            dinv[node]    = rsqrtf((float)(hist[t] + 1));
        }
    }
    __syncthreads();
    for (int i = t; i < ne; i += 256) {
        unsigned pe = ebuf[base + i];
        int dl = pe >> 17;
        int pos = atomicAdd(&cur[dl], 1);  // LDS int atomic
        csr[base + pos] = (int)(pe & 0x1FFFF);
    }
}

// ---- MFMA GEMM 1 (LDS-free): hp[n][d] = bf16( dinv[n] * sum_k x[n][k] W[k][d] )
// A = W^T (d x k, bf16, L1/L2-hot), B = x rows (node per l15); D: row=d-local, col=node
__global__ __launch_bounds__(256) void k_gemm1(const float* __restrict__ x,
                                               const ushort_t* __restrict__ wtb,
                                               const float* __restrict__ dinv,
                                               ushort_t* __restrict__ hp) {
    int t = threadIdx.x;
    int w = t >> 6, lane = t & 63, l15 = lane & 15, quad = lane >> 4;
    int gn = blockIdx.x * 64 + w * 16 + l15;
    int gnc = gn < NN ? gn : NN - 1;
    const float*    xp = x   + (size_t)gnc * 128 + quad * 8;
    const ushort_t* wp = wtb + l15 * 128 + quad * 8;
    f32x4 acc[4];
#pragma unroll
    for (int dt = 0; dt < 4; ++dt) { acc[dt][0]=0.f; acc[dt][1]=0.f; acc[dt][2]=0.f; acc[dt][3]=0.f; }

#pragma unroll
    for (int kt = 0; kt < 4; ++kt) {
        float4 v0 = *(const float4*)(xp + kt * 32);
        float4 v1 = *(const float4*)(xp + kt * 32 + 4);
        union { ushort_t u[8]; bf16x8 v; } cv;
        cv.u[0]=f2bf(v0.x); cv.u[1]=f2bf(v0.y); cv.u[2]=f2bf(v0.z); cv.u[3]=f2bf(v0.w);
        cv.u[4]=f2bf(v1.x); cv.u[5]=f2bf(v1.y); cv.u[6]=f2bf(v1.z); cv.u[7]=f2bf(v1.w);
        bf16x8 bv = cv.v;
#pragma unroll
        for (int dt = 0; dt < 4; ++dt) {
            bf16x8 av = *(const bf16x8*)(wp + dt * 16 * 128 + kt * 32);
            acc[dt] = __builtin_amdgcn_mfma_f32_16x16x32_bf16(av, bv, acc[dt], 0, 0, 0);
        }
    }
    if (gn < NN) {
        float dv = dinv[gn];
#pragma unroll
        for (int dt = 0; dt < 4; ++dt) {
            // D row = quad*4+reg (d-local), col = l15 (node) -> 4 consecutive d per lane
            uint2 o;
            o.x = (unsigned)f2bf(dv * acc[dt][0]) | ((unsigned)f2bf(dv * acc[dt][1]) << 16);
            o.y = (unsigned)f2bf(dv * acc[dt][2]) | ((unsigned)f2bf(dv * acc[dt][3]) << 16);
            *(uint2*)&hp[(size_t)gn * 64 + dt * 16 + quad * 4] = o;
        }
    }
}

// ---- gather-side aggregation: 4 nodes per wave, one 16-lane group per node.
// Group's 16 lanes x uint2 = full 128B hp row; no cross-group reduce; all lanes store.
__global__ __launch_bounds__(256) void k_gather(const int* __restrict__ offsets,
                                                const int* __restrict__ deg,
                                                const int* __restrict__ csr,
                                                const float* __restrict__ dinv,
                                                const ushort_t* __restrict__ hp,
                                                const float* __restrict__ b_conv,
                                                ushort_t* __restrict__ a) {
    int t = threadIdx.x;
    int lane = t & 63;
    int g = lane >> 4, l16 = lane & 15;
    int wave = (blockIdx.x * 256 + t) >> 6;     // 0..24999
    int node = wave * 4 + g;                    // group-uniform, < NN (6250*16*... = exact)
    int start = offsets[node];
    int cnt   = deg[node];
    const ushort_t* hpc = hp + l16 * 4;

    // wave-uniform round count = max cnt over the 4 groups
    int cmax = cnt;
    { int o1 = __shfl_xor(cmax, 16, 64); cmax = cmax > o1 ? cmax : o1;
      int o2 = __shfl_xor(cmax, 32, 64); cmax = cmax > o2 ? cmax : o2; }

    float s0 = 0.f, s1 = 0.f, s2 = 0.f, s3 = 0.f;
#pragma unroll 1
    for (int j0 = 0; j0 < cmax; j0 += 16) {
        int col = 0;
        if (j0 + l16 < cnt) col = csr[start + j0 + l16];
        int mg = cnt - j0;                      // group-uniform remaining
#pragma unroll
        for (int jj = 0; jj < 16; jj += 8) {
            int cc[8]; uint2 dd[8];
#pragma unroll
            for (int u = 0; u < 8; ++u)
                cc[u] = __shfl(col, (lane & 48) + jj + u, 64);
#pragma unroll
            for (int u = 0; u < 8; ++u) {
                int c = (jj + u < mg) ? cc[u] : node;   // clamp to own (hot) row
                dd[u] = *(const uint2*)(hpc + (size_t)c * 64);
            }
#pragma unroll
            for (int u = 0; u < 8; ++u) {
                if (jj + u >= mg) { dd[u].x = 0u; dd[u].y = 0u; }
                s0 += bf2f(dd[u].x); s1 += bf2f_hi(dd[u].x);
                s2 += bf2f(dd[u].y); s3 += bf2f_hi(dd[u].y);
            }
        }
    }
    // self-loop + bias + relu
    uint2 sl = *(const uint2*)(hpc + (size_t)node * 64);
    s0 += bf2f(sl.x); s1 += bf2f_hi(sl.x); s2 += bf2f(sl.y); s3 += bf2f_hi(sl.y);
    float dv = dinv[node];
    float4 bc = *(const float4*)(b_conv + l16 * 4);
    float v0 = fmaxf(dv * s0 + bc.x, 0.f);
    float v1 = fmaxf(dv * s1 + bc.y, 0.f);
    float v2 = fmaxf(dv * s2 + bc.z, 0.f);
    float v3 = fmaxf(dv * s3 + bc.w, 0.f);
    uint2 o;
    o.x = (unsigned)f2bf(v0) | ((unsigned)f2bf(v1) << 16);
    o.y = (unsigned)f2bf(v2) | ((unsigned)f2bf(v3) << 16);
    *(uint2*)&a[(size_t)node * 64 + l16 * 4] = o;
}

// ---- MFMA epilogue GEMM (LDS-free): out[n][j] = sum_k a[n][k] W2[k][j] + b_lin[j]
__global__ __launch_bounds__(256) void k_epi(const ushort_t* __restrict__ a,
                                             const ushort_t* __restrict__ w2tb,
                                             const float* __restrict__ blin,
                                             float* __restrict__ out) {
    int t = threadIdx.x;
    int w = t >> 6, lane = t & 63, l15 = lane & 15, quad = lane >> 4;
    int gn = blockIdx.x * 64 + w * 16 + l15;
    int gnc = gn < NN ? gn : NN - 1;
    const ushort_t* ap = a    + (size_t)gnc * 64 + quad * 8;
    const ushort_t* wp = w2tb + l15 * 64 + quad * 8;
    f32x4 acc[8];
#pragma unroll
    for (int jt = 0; jt < 8; ++jt) { acc[jt][0]=0.f; acc[jt][1]=0.f; acc[jt][2]=0.f; acc[jt][3]=0.f; }

#pragma unroll
    for (int kt = 0; kt < 2; ++kt) {
        bf16x8 bv = *(const bf16x8*)(ap + kt * 32);
#pragma unroll
        for (int jt = 0; jt < 8; ++jt) {
            bf16x8 av = *(const bf16x8*)(wp + jt * 16 * 64 + kt * 32);
            acc[jt] = __builtin_amdgcn_mfma_f32_16x16x32_bf16(av, bv, acc[jt], 0, 0, 0);
        }
    }
    if (gn < NN) {
#pragma unroll
        for (int jt = 0; jt < 8; ++jt) {
            int j0 = jt * 16 + quad * 4;
            float4 b4 = *(const float4*)(blin + j0);
            float4 o;
            o.x = acc[jt][0] + b4.x; o.y = acc[jt][1] + b4.y;
            o.z = acc[jt][2] + b4.z; o.w = acc[jt][3] + b4.w;
            *(float4*)&out[(size_t)gn * 128 + j0] = o;
        }
    }
}

extern "C" void kernel_launch(void* const* d_in, const int* in_sizes, int n_in,
                              void* d_out, int out_size, void* d_ws, size_t ws_size,
                              hipStream_t stream) {
    const float* x  = (const float*)d_in[0];
    const int*   ei = (const int*)d_in[1];
    const float* Wc = (const float*)d_in[2];
    const float* bc = (const float*)d_in[3];
    const float* Wl = (const float*)d_in[4];
    const float* bl = (const float*)d_in[5];
    float* out = (float*)d_out;

    char* ws = (char*)d_ws;
    // total ~49.7 MB (ws_size = 256 MiB); every byte written before read -> no memset
    int*      bhist     = (int*)(ws + 0);              // 1600*782*4 = 5004800
    int*      base_excl = (int*)(ws + 5004800);        // 5004800
    int*      coltot    = (int*)(ws + 10009600);       // 3200
    int*      bstart    = (int*)(ws + 10012800);       // 3200
    int*      bcnt      = (int*)(ws + 10016000);       // 3200
    int*      offsets   = (int*)(ws + 10019200);       // 400384
    int*      deg       = (int*)(ws + 10419584);       // 400384
    float*    dinv      = (float*)(ws + 10819968);     // 400384
    ushort_t* wtb       = (ushort_t*)(ws + 11220352);  // 16384
    ushort_t* w2tb      = (ushort_t*)(ws + 11236736);  // 16384
    unsigned* ebuf      = (unsigned*)(ws + 11253120);  // 6400000
    int*      csr       = (int*)(ws + 17653120);       // 6400000
    ushort_t* hp        = (ushort_t*)(ws + 24053120);  // 12800000 (bf16)
    ushort_t* a         = (ushort_t*)(ws + 36853120);  // 12800000 (bf16)

    k_pre     <<<NBLK + 32, 256, 0, stream>>>(ei, Wc, Wl, bhist, wtb, w2tb);
    k_colscan <<<NBUK, 512, 0, stream>>>(bhist, base_excl, coltot);
    k_scanb2  <<<1, 1024, 0, stream>>>(coltot, bstart, bcnt);
    k_scatter2<<<NBLK, 256, 0, stream>>>(ei, bstart, base_excl, ebuf);
    k_sort    <<<NBUK, 256, 0, stream>>>(bstart, bcnt, ebuf, csr, offsets, deg, dinv);
    k_gemm1   <<<NGB, 256, 0, stream>>>(x, wtb, dinv, hp);
    k_gather  <<<NN / 16, 256, 0, stream>>>(offsets, deg, csr, dinv, hp, bc, a);
    k_epi     <<<NGB, 256, 0, stream>>>(a, w2tb, bl, out);
}